// Round 5
// baseline (360.436 us; speedup 1.0000x reference)
//
#include <hip/hip_runtime.h>

// ---------------------------------------------------------------------------
// Fused 2-layer LSTM, N=8192, T=28, I=28, H=128, + final [128->10] linear.
// R5: single-barrier software-pipelined step (R4 layout, new schedule).
//   Iteration t computes L0(t) AND L1(t-1) in one region: both read only
//   data >=1 barrier old (h0(t-1), h1(t-2)) -> ONE __syncthreads per
//   iteration, and the two layers' MFMA/trans/LDS streams interleave to
//   hide each other's latency (R4 was 78% stall: 2-barrier lockstep with
//   1 wave/SIMD exposed every dependent chain).
//   h0(t-1) A-frags shared between whh0-MFMA (L0) and wih1-MFMA (L1).
// Resources: 256 thr (4 waves), 1 wave/SIMD, 512-reg budget; weights
//   whh0+whh1+wih0 resident (288 regs), wih1 in LDS (128 KB).
// LDS = 128K (wih1) + 8K (h0 x2) + 8K (h1 x2) = 144 KB.
// ---------------------------------------------------------------------------

typedef short  short8   __attribute__((ext_vector_type(8)));
typedef float  float4_t __attribute__((ext_vector_type(4)));

#define WIH1_OFF 0        // 131072 B : wih1 [4kc][32nt][64 lane][8] bf16 frags
#define H0_OFF   131072   //   8192 B : h0, 2 buffers x 4096
#define H1_OFF   139264   //   8192 B : h1, 2 buffers x 4096
#define SMEM_SZ  147456

__device__ __forceinline__ unsigned short bf16r(float v) {
  union { float f; unsigned u; } x; x.f = v;
  unsigned r = x.u + 0x7fffu + ((x.u >> 16) & 1u);   // round-to-nearest-even
  return (unsigned short)(r >> 16);
}
__device__ __forceinline__ float bf2f(unsigned short b) {
  union { unsigned u; float f; } x; x.u = ((unsigned)b) << 16;
  return x.f;
}
__device__ __forceinline__ float sigf(float x)  { return 1.0f / (1.0f + __expf(-x)); }
__device__ __forceinline__ float tanhfast(float x) { return 1.0f - 2.0f / (__expf(2.0f * x) + 1.0f); }

// ---------------------------------------------------------------------------
// Prologue: pack weights (fp32 -> bf16) into MFMA B-frag tiled layout in ws.
// ws (unsigned short units):
//   [0      ,16384) : w_ih0  [1 kc][32 tiles][64 lanes][8] (k padded to 32;
//                     k==28 slot holds bih0+bhh0 -> bias folded into x-MFMA)
//   [16384  ,81920) : w_hh0  [4 kc][32 tiles][64][8]
//   [81920 ,147456) : w_ih1  [4 kc][32][64][8]
//   [147456,212992) : w_hh1  [4 kc][32][64][8]
// element (tile,lane,j): row = tile*16 + (lane&15), k = kc*32 + (lane>>4)*8 + j
// ---------------------------------------------------------------------------
__global__ void pack_weights(const float* __restrict__ wih0, const float* __restrict__ whh0,
                             const float* __restrict__ wih1, const float* __restrict__ whh1,
                             const float* __restrict__ bih0, const float* __restrict__ bhh0,
                             unsigned short* __restrict__ dst)
{
  int e = blockIdx.x * 256 + threadIdx.x;
  const float* src; int K; int i; bool isW0 = false;
  if      (e < 16384)  { src = wih0; K = 28;  i = e;          isW0 = true; }
  else if (e < 81920)  { src = whh0; K = 128; i = e - 16384;  }
  else if (e < 147456) { src = wih1; K = 128; i = e - 81920;  }
  else if (e < 212992) { src = whh1; K = 128; i = e - 147456; }
  else return;
  int j = i & 7, lane = (i >> 3) & 63, tile = (i >> 9) & 31, kc = i >> 14;
  int row = tile * 16 + (lane & 15);
  int k = kc * 32 + ((lane >> 4) << 3) + j;
  float v;
  if (k < K)                 v = src[row * K + k];
  else if (isW0 && k == 28)  v = bih0[row] + bhh0[row];   // folded bias0
  else                       v = 0.0f;
  dst[e] = bf16r(v);
}

// ---------------------------------------------------------------------------
// Main fused kernel. grid 256 x 256 threads (4 waves), 1 wave/SIMD.
// Wave w owns gate-rows nt = g*8 + 2w + hs (g=0..3, hs=0..1)
//   -> h-dims [32w, 32w+32) for every gate (c-update stays thread-local).
// ---------------------------------------------------------------------------
__global__ __launch_bounds__(256, 1)
__attribute__((amdgpu_waves_per_eu(1, 1)))
void lstm_fused(const float* __restrict__ xg,
                const unsigned short* __restrict__ wpack,
                const float* __restrict__ bih1, const float* __restrict__ bhh1,
                const float* __restrict__ wout, const float* __restrict__ bout,
                float* __restrict__ out)
{
  __shared__ __align__(16) char smem[SMEM_SZ];

  const int tid  = threadIdx.x;
  const int lane = tid & 63;
  const int w    = tid >> 6;          // wave 0..3
  const int q    = lane >> 4;         // quad -> acc rows (samples) q*4..q*4+3
  const int mcol = lane & 15;         // acc col = gate-dim within tile

  const short8* wp = (const short8*)wpack;

  // ---- persistent weight slices in registers (288 regs) ------------------
  short8 whh0[4][8], whh1[4][8], wih0[8];      // [kc][g*2+hs] / [g*2+hs]
#pragma unroll
  for (int kc = 0; kc < 4; ++kc)
#pragma unroll
    for (int g = 0; g < 4; ++g)
#pragma unroll
      for (int hs = 0; hs < 2; ++hs) {
        whh0[kc][g * 2 + hs] = wp[ 2048 + (kc * 32 + g * 8 + 2 * w + hs) * 64 + lane];
        whh1[kc][g * 2 + hs] = wp[18432 + (kc * 32 + g * 8 + 2 * w + hs) * 64 + lane];
      }
#pragma unroll
  for (int g = 0; g < 4; ++g)
#pragma unroll
    for (int hs = 0; hs < 2; ++hs)
      wih0[g * 2 + hs] = wp[(g * 8 + 2 * w + hs) * 64 + lane];

  // ---- wih1 -> LDS (131072 B) --------------------------------------------
  {
    short8* wl = (short8*)smem;
#pragma unroll
    for (int r = 0; r < 32; ++r)
      wl[r * 256 + tid] = wp[10240 + r * 256 + tid];
  }

  // ---- bias1 (8 regs) -----------------------------------------------------
  float bias1[8];
#pragma unroll
  for (int g = 0; g < 4; ++g)
#pragma unroll
    for (int hs = 0; hs < 2; ++hs) {
      int d = g * 128 + (2 * w + hs) * 16 + mcol;
      bias1[g * 2 + hs] = bih1[d] + bhh1[d];
    }

  // per-lane constant part of the h-write address: element (s, d),
  // d = (2w+hs)*16+mcol -> kc-chunk w, lane' = (2hs+(mcol>>3))*16 + s, j=mcol&7
  const int hwc = w * 1024 + ((mcol >> 3) << 8) + (q << 6) + ((mcol & 7) << 1);

  const short8* W1 = (const short8*)smem;    // wih1 frags [kc*32+nt][lane]

#pragma unroll 1
  for (int half = 0; half < 2; ++half) {
    const int n0 = blockIdx.x * 32 + half * 16;

    // zero parity-1 h buffers (t=0 reads h0 p1; t=1 reads h1 p1)
    {
      int* z0 = (int*)(smem + H0_OFF + 4096);
      int* z1 = (int*)(smem + H1_OFF + 4096);
#pragma unroll
      for (int r = 0; r < 4; ++r) { z0[r * 256 + tid] = 0; z1[r * 256 + tid] = 0; }
    }

    float cst0[8], cst1[8];
#pragma unroll
    for (int i = 0; i < 8; ++i) { cst0[i] = 0.f; cst1[i] = 0.f; }

    // x A-frag loader: sample m = mcol, k = q*8+j; k==28 -> 1.0 (bias slot)
    float4_t xlo, xhi;
    auto load_x = [&](int t) {
      const float* p = xg + (size_t)(n0 + mcol) * 784 + t * 28 + q * 8;
      xlo = *(const float4_t*)p;
      xhi = (q < 3) ? *(const float4_t*)(p + 4) : (float4_t){1.f, 0.f, 0.f, 0.f};
    };
    load_x(0);
    __syncthreads();   // wih1 staged / h zeroed / prev epilogue done

    // ---- pipelined recurrence: iter t does L0(t) and L1(t-1) -------------
#pragma unroll 1
    for (int t = 0; t <= 28; ++t) {
      const char* h0p = smem + H0_OFF + ((t + 1) & 1) * 4096;   // h0(t-1)
      char*       h0c = smem + H0_OFF + (t & 1) * 4096;         // h0(t)
      const char* h1p = smem + H1_OFF + (t & 1) * 4096;         // h1(t-2)
      char*       h1c = smem + H1_OFF + ((t + 1) & 1) * 4096;   // h1(t-1)

      // h0(t-1) frags: shared by L0's whh0-MFMA and L1's wih1-MFMA
      short8 ha[4];
#pragma unroll
      for (int kc = 0; kc < 4; ++kc)
        ha[kc] = ((const short8*)h0p)[kc * 64 + lane];

      // ============ L1(t-1): gates = b1 + h0(t-1)@wih1 + h1(t-2)@whh1 =====
      float4_t ac1[8];
      if (t >= 1) {
        short8 hc[4];
#pragma unroll
        for (int kc = 0; kc < 4; ++kc)
          hc[kc] = ((const short8*)h1p)[kc * 64 + lane];
#pragma unroll
        for (int i = 0; i < 8; ++i) {
          float b = bias1[i];
          ac1[i] = (float4_t){b, b, b, b};
        }
#pragma unroll
        for (int kc = 0; kc < 4; ++kc)
#pragma unroll
          for (int i = 0; i < 8; ++i)
            ac1[i] = __builtin_amdgcn_mfma_f32_16x16x32_bf16(
                        ha[kc], W1[(kc * 32 + (i >> 1) * 8 + 2 * w + (i & 1)) * 64 + lane],
                        ac1[i], 0, 0, 0);
#pragma unroll
        for (int kc = 0; kc < 4; ++kc)
#pragma unroll
          for (int i = 0; i < 8; ++i)
            ac1[i] = __builtin_amdgcn_mfma_f32_16x16x32_bf16(hc[kc], whh1[kc][i], ac1[i], 0, 0, 0);
      }

      // ============ L0(t): gates = x_t@[wih0|b0] + h0(t-1)@whh0 ===========
      if (t < 28) {
        short8 xf;
#pragma unroll
        for (int j = 0; j < 4; ++j) {
          xf[j]     = (short)bf16r(xlo[j]);
          xf[j + 4] = (short)bf16r(xhi[j]);
        }
        if (t + 1 < 28) load_x(t + 1);         // prefetch next iter's x
        float4_t ac0[8];
#pragma unroll
        for (int i = 0; i < 8; ++i)
          ac0[i] = __builtin_amdgcn_mfma_f32_16x16x32_bf16(xf, wih0[i],
                      (float4_t){0.f, 0.f, 0.f, 0.f}, 0, 0, 0);
#pragma unroll
        for (int kc = 0; kc < 4; ++kc)
#pragma unroll
          for (int i = 0; i < 8; ++i)
            ac0[i] = __builtin_amdgcn_mfma_f32_16x16x32_bf16(ha[kc], whh0[kc][i], ac0[i], 0, 0, 0);
        // activations (i,f,g,o) + h0(t) write
#pragma unroll
        for (int hs = 0; hs < 2; ++hs)
#pragma unroll
          for (int r = 0; r < 4; ++r) {
            float ig = sigf(ac0[0 + hs][r]), fg = sigf(ac0[2 + hs][r]);
            float gg = tanhfast(ac0[4 + hs][r]), og = sigf(ac0[6 + hs][r]);
            float c  = fg * cst0[hs * 4 + r] + ig * gg;
            cst0[hs * 4 + r] = c;
            *(unsigned short*)(h0c + hs * 512 + r * 16 + hwc) = bf16r(og * tanhfast(c));
          }
      }

      // ============ L1(t-1) activations + h1(t-1) write ===================
      if (t >= 1) {
#pragma unroll
        for (int hs = 0; hs < 2; ++hs)
#pragma unroll
          for (int r = 0; r < 4; ++r) {
            float ig = sigf(ac1[0 + hs][r]), fg = sigf(ac1[2 + hs][r]);
            float gg = tanhfast(ac1[4 + hs][r]), og = sigf(ac1[6 + hs][r]);
            float c  = fg * cst1[hs * 4 + r] + ig * gg;
            cst1[hs * 4 + r] = c;
            *(unsigned short*)(h1c + hs * 512 + r * 16 + hwc) = bf16r(og * tanhfast(c));
          }
      }
      __syncthreads();   // all reads/writes of this iter done
    }

    // ============ epilogue: out[s][o] = h1(27) . wout[o] + bout[o] =========
    // t=28 wrote h1(27) into parity 1.
    const short8* H1f = (const short8*)(smem + H1_OFF + 4096);
    if (tid < 160) {
      int s = tid / 10, o = tid - (tid / 10) * 10;
      float sum = bout[o];
#pragma unroll
      for (int kc = 0; kc < 4; ++kc)
#pragma unroll
        for (int sb = 0; sb < 4; ++sb) {
          short8 hv = H1f[kc * 64 + sb * 16 + s];
          int dbase = kc * 32 + sb * 8;
          float4_t w0 = *(const float4_t*)(wout + o * 128 + dbase);
          float4_t w1 = *(const float4_t*)(wout + o * 128 + dbase + 4);
#pragma unroll
          for (int j = 0; j < 4; ++j) {
            sum += bf2f((unsigned short)hv[j])     * w0[j];
            sum += bf2f((unsigned short)hv[j + 4]) * w1[j];
          }
        }
      out[(size_t)(n0 + s) * 10 + o] = sum;
    }
    __syncthreads();   // epilogue reads done before next half re-zeroes
  }
}

extern "C" void kernel_launch(void* const* d_in, const int* in_sizes, int n_in,
                              void* d_out, int out_size, void* d_ws, size_t ws_size,
                              hipStream_t stream) {
  const float* x    = (const float*)d_in[0];
  const float* wih0 = (const float*)d_in[1];
  const float* whh0 = (const float*)d_in[2];
  const float* bih0 = (const float*)d_in[3];
  const float* bhh0 = (const float*)d_in[4];
  const float* wih1 = (const float*)d_in[5];
  const float* whh1 = (const float*)d_in[6];
  const float* bih1 = (const float*)d_in[7];
  const float* bhh1 = (const float*)d_in[8];
  const float* wout = (const float*)d_in[9];
  const float* bout = (const float*)d_in[10];

  unsigned short* wp = (unsigned short*)d_ws;   // 425984 B used

  pack_weights<<<832, 256, 0, stream>>>(wih0, whh0, wih1, whh1, bih0, bhh0, wp);
  lstm_fused<<<256, 256, 0, stream>>>(x, wp, bih1, bhh1, wout, bout, (float*)d_out);
}

// Round 6
// 313.438 us; speedup vs baseline: 1.1499x; 1.1499x over previous
//
#include <hip/hip_runtime.h>

// ---------------------------------------------------------------------------
// Fused 2-layer LSTM, N=8192, T=28, I=28, H=128, + final [128->10] linear.
// R6: R2 skeleton (8 waves, 2/SIMD, 16-dim slices, 2 barriers/step) rebuilt
//     for REGISTER SLACK + LOAD BATCHING:
//  * mt-sequential phases: acc 16 live (R2: 32) -> scheduler headroom.
//  * frag reads batched per group (1 lgkmcnt wait per 4, not per 1).
//  * h1 frag loads issued under the wih1 MFMA chain (latency hidden).
//  * bias0 folded into x k=28 pad slot; h1 single-buffered, writes deferred
//    past B_end into the LDS-light L0 phase of the next iteration.
// Theory: R2/R4/R5 all ran at the register cap -> no load batching -> ~50%
// stall on exposed ds_read latency. Demand now ~200-240 of 256.
// LDS = 128K wih1 + 16K h0(x2) + 8K h1 + 2K x = 157696 B.
// ---------------------------------------------------------------------------

typedef short  short8   __attribute__((ext_vector_type(8)));
typedef float  float4_t __attribute__((ext_vector_type(4)));
typedef float  float2_t __attribute__((ext_vector_type(2)));

#define WIH1_OFF 0        // 131072 B : wih1 [4kc][32nt][64 lane][8]
#define H0_OFF   131072   //  16384 B : h0, 2 buffers x 8192
#define H1_OFF   147456   //   8192 B : h1, single buffer
#define X_OFF    155648   //   2048 B : x tile (k padded to 32; k=28 = 1.0)
#define SMEM_SZ  157696

__device__ __forceinline__ unsigned short bf16r(float v) {
  union { float f; unsigned u; } x; x.f = v;
  unsigned r = x.u + 0x7fffu + ((x.u >> 16) & 1u);
  return (unsigned short)(r >> 16);
}
__device__ __forceinline__ float bf2f(unsigned short b) {
  union { unsigned u; float f; } x; x.u = ((unsigned)b) << 16;
  return x.f;
}
__device__ __forceinline__ float sigf(float x)  { return 1.0f / (1.0f + __expf(-x)); }
__device__ __forceinline__ float tanhfast(float x) { return 1.0f - 2.0f / (__expf(2.0f * x) + 1.0f); }

// ---------------------------------------------------------------------------
// pack_weights: fp32 -> bf16 MFMA B-frag tiles in ws (same as R4/R5).
// wih0 k=28 slot holds bih0+bhh0 (bias folded into the x-MFMA).
// ---------------------------------------------------------------------------
__global__ void pack_weights(const float* __restrict__ wih0, const float* __restrict__ whh0,
                             const float* __restrict__ wih1, const float* __restrict__ whh1,
                             const float* __restrict__ bih0, const float* __restrict__ bhh0,
                             unsigned short* __restrict__ dst)
{
  int e = blockIdx.x * 256 + threadIdx.x;
  const float* src; int K; int i; bool isW0 = false;
  if      (e < 16384)  { src = wih0; K = 28;  i = e;          isW0 = true; }
  else if (e < 81920)  { src = whh0; K = 128; i = e - 16384;  }
  else if (e < 147456) { src = wih1; K = 128; i = e - 81920;  }
  else if (e < 212992) { src = whh1; K = 128; i = e - 147456; }
  else return;
  int j = i & 7, lane = (i >> 3) & 63, tile = (i >> 9) & 31, kc = i >> 14;
  int row = tile * 16 + (lane & 15);
  int k = kc * 32 + ((lane >> 4) << 3) + j;
  float v;
  if (k < K)                 v = src[row * K + k];
  else if (isW0 && k == 28)  v = bih0[row] + bhh0[row];
  else                       v = 0.0f;
  dst[e] = bf16r(v);
}

// ---------------------------------------------------------------------------
// Main kernel: 256 blocks x 512 threads (8 waves, 2/SIMD). Wave w owns
// h-dims [16w, 16w+16) of every gate for both layers.
// ---------------------------------------------------------------------------
__global__ __launch_bounds__(512)
__attribute__((amdgpu_waves_per_eu(2, 2)))
void lstm_fused(const float* __restrict__ xg,
                const unsigned short* __restrict__ wpack,
                const float* __restrict__ bih1, const float* __restrict__ bhh1,
                const float* __restrict__ wout, const float* __restrict__ bout,
                float* __restrict__ out)
{
  __shared__ __align__(16) char smem[SMEM_SZ];

  const int tid  = threadIdx.x;
  const int lane = tid & 63;
  const int w    = tid >> 6;          // 0..7
  const int q    = lane >> 4;
  const int mcol = lane & 15;
  const int n0   = blockIdx.x * 32;

  const short8* wp = (const short8*)wpack;

  // ---- resident weights: 36 frags = 144 regs -----------------------------
  short8 wih0[4], whh0[4][4], whh1[4][4];
#pragma unroll
  for (int g = 0; g < 4; ++g)
    wih0[g] = wp[(g * 8 + w) * 64 + lane];
#pragma unroll
  for (int kc = 0; kc < 4; ++kc)
#pragma unroll
    for (int g = 0; g < 4; ++g) {
      whh0[kc][g] = wp[ 2048 + (kc * 32 + g * 8 + w) * 64 + lane];
      whh1[kc][g] = wp[18432 + (kc * 32 + g * 8 + w) * 64 + lane];
    }

  // ---- wih1 -> LDS --------------------------------------------------------
  {
    short8* wl = (short8*)smem;
#pragma unroll
    for (int r = 0; r < 16; ++r)
      wl[r * 512 + tid] = wp[10240 + r * 512 + tid];
  }

  // ---- bias1: 4 regs ------------------------------------------------------
  float bias1[4];
#pragma unroll
  for (int g = 0; g < 4; ++g)
    bias1[g] = bih1[g * 128 + w * 16 + mcol] + bhh1[g * 128 + w * 16 + mcol];

  // ---- zero h0 parity-1 + h1 ---------------------------------------------
  {
    int* z0 = (int*)(smem + H0_OFF + 8192);
    int* z1 = (int*)(smem + H1_OFF);
#pragma unroll
    for (int r = 0; r < 4; ++r) { z0[r * 512 + tid] = 0; z1[r * 512 + tid] = 0; }
  }

  // ---- x pad: k=28 -> 1.0 (bias slot), k=29..31 -> 0 ---------------------
  if (tid < 32) {
    char* p = smem + X_OFF + (tid >> 4) * 1024 + (48 + (tid & 15)) * 16;
    *(unsigned*)(p + 8)  = 0x00003F80u;   // bf16 1.0 at j=4, 0 at j=5
    *(unsigned*)(p + 12) = 0u;            // j=6,7
  }

  // ---- x staging (tid<448): one float2 per thread per step ---------------
  const int xs_s = tid / 14;
  const int xs_k = (tid - xs_s * 14) * 2;
  const float* xs_base = xg + (size_t)(n0 + xs_s) * 784 + xs_k;
  char* const xs_dst = smem + X_OFF + (xs_s >> 4) * 1024 +
                       ((xs_k >> 3) * 16 + (xs_s & 15)) * 16 + (xs_k & 7) * 2;
  if (tid < 448) {
    float2_t v = *(const float2_t*)xs_base;
    *(unsigned*)xs_dst = (unsigned)bf16r(v[0]) | ((unsigned)bf16r(v[1]) << 16);
  }

  // per-lane h-write base: element (s, d) with d = 16w + mcol
  const int hwc = (w >> 1) * 1024 + (((w & 1) << 1) | (mcol >> 3)) * 256 +
                  q * 64 + (mcol & 7) * 2;

  const short8* Xf = (const short8*)(smem + X_OFF);
  const short8* W1 = (const short8*)smem;

  float c0[8], c1[8];
  unsigned short hb1[8];
#pragma unroll
  for (int i = 0; i < 8; ++i) { c0[i] = 0.f; c1[i] = 0.f; hb1[i] = 0; }

  __syncthreads();

#pragma unroll 1
  for (int t = 0; t < 28; ++t) {
    const char* h0p = smem + H0_OFF + ((t + 1) & 1) * 8192;
    char*       h0c = smem + H0_OFF + (t & 1) * 8192;

    // -- deferred h1(t-1) writes (LDS-light phase; after B_end(t-1)) -------
#pragma unroll
    for (int mt = 0; mt < 2; ++mt)
#pragma unroll
      for (int r = 0; r < 4; ++r)
        *(unsigned short*)(smem + H1_OFF + mt * 4096 + r * 16 + hwc) = hb1[mt * 4 + r];

    // ================= L0(t): mt-sequential ==============================
#pragma unroll
    for (int mt = 0; mt < 2; ++mt) {
      short8 ha[4];
#pragma unroll
      for (int kc = 0; kc < 4; ++kc)           // batched group
        ha[kc] = ((const short8*)h0p)[(mt * 4 + kc) * 64 + lane];
      short8 xf = Xf[mt * 64 + lane];
      float4_t ac[4];
#pragma unroll
      for (int g = 0; g < 4; ++g)
        ac[g] = __builtin_amdgcn_mfma_f32_16x16x32_bf16(xf, wih0[g],
                    (float4_t){0.f, 0.f, 0.f, 0.f}, 0, 0, 0);
#pragma unroll
      for (int kc = 0; kc < 4; ++kc)
#pragma unroll
        for (int g = 0; g < 4; ++g)
          ac[g] = __builtin_amdgcn_mfma_f32_16x16x32_bf16(ha[kc], whh0[kc][g], ac[g], 0, 0, 0);
#pragma unroll
      for (int r = 0; r < 4; ++r) {
        float ig = sigf(ac[0][r]), fg = sigf(ac[1][r]);
        float gg = tanhfast(ac[2][r]), og = sigf(ac[3][r]);
        float c  = fg * c0[mt * 4 + r] + ig * gg;
        c0[mt * 4 + r] = c;
        *(unsigned short*)(h0c + mt * 4096 + r * 16 + hwc) = bf16r(og * tanhfast(c));
      }
    }
    __syncthreads();   // B_mid: h0(t) visible; x(t) reads done

    // ================= L1(t): mt-sequential ==============================
    float2_t xv = (float2_t){0.f, 0.f};
    if (t < 27 && tid < 448) xv = *(const float2_t*)(xs_base + (t + 1) * 28);

#pragma unroll
    for (int mt = 0; mt < 2; ++mt) {
      short8 hb[4], hc[4];
#pragma unroll
      for (int kc = 0; kc < 4; ++kc)           // batched: h0(t) frags
        hb[kc] = ((const short8*)h0c)[(mt * 4 + kc) * 64 + lane];
#pragma unroll
      for (int kc = 0; kc < 4; ++kc)           // issued early, used late
        hc[kc] = ((const short8*)(smem + H1_OFF))[(mt * 4 + kc) * 64 + lane];
      float4_t ac[4];
#pragma unroll
      for (int g = 0; g < 4; ++g)
        ac[g] = (float4_t){bias1[g], bias1[g], bias1[g], bias1[g]};
#pragma unroll
      for (int kc = 0; kc < 4; ++kc) {         // wih1 chain (hides hc loads)
        short8 wf[4];
#pragma unroll
        for (int g = 0; g < 4; ++g)
          wf[g] = W1[(kc * 32 + g * 8 + w) * 64 + lane];
#pragma unroll
        for (int g = 0; g < 4; ++g)
          ac[g] = __builtin_amdgcn_mfma_f32_16x16x32_bf16(hb[kc], wf[g], ac[g], 0, 0, 0);
      }
#pragma unroll
      for (int kc = 0; kc < 4; ++kc)
#pragma unroll
        for (int g = 0; g < 4; ++g)
          ac[g] = __builtin_amdgcn_mfma_f32_16x16x32_bf16(hc[kc], whh1[kc][g], ac[g], 0, 0, 0);
#pragma unroll
      for (int r = 0; r < 4; ++r) {
        float ig = sigf(ac[0][r]), fg = sigf(ac[1][r]);
        float gg = tanhfast(ac[2][r]), og = sigf(ac[3][r]);
        float c  = fg * c1[mt * 4 + r] + ig * gg;
        c1[mt * 4 + r] = c;
        hb1[mt * 4 + r] = bf16r(og * tanhfast(c));   // deferred write
      }
    }
    if (t < 27 && tid < 448)
      *(unsigned*)xs_dst = (unsigned)bf16r(xv[0]) | ((unsigned)bf16r(xv[1]) << 16);
    __syncthreads();   // B_end: h1(t-1)/x(t) reads done; x(t+1) staged
  }

  // ---- final h1(27) writes + epilogue ------------------------------------
#pragma unroll
  for (int mt = 0; mt < 2; ++mt)
#pragma unroll
    for (int r = 0; r < 4; ++r)
      *(unsigned short*)(smem + H1_OFF + mt * 4096 + r * 16 + hwc) = hb1[mt * 4 + r];
  __syncthreads();

  const short8* H1f = (const short8*)(smem + H1_OFF);
  if (tid < 320) {
    int s = tid / 10, o = tid - (tid / 10) * 10;
    float sum = bout[o];
#pragma unroll
    for (int kc = 0; kc < 4; ++kc)
#pragma unroll
      for (int sb = 0; sb < 4; ++sb) {
        short8 hv = H1f[((s >> 4) * 4 + kc) * 64 + sb * 16 + (s & 15)];
        int dbase = kc * 32 + sb * 8;
        float4_t w0 = *(const float4_t*)(wout + o * 128 + dbase);
        float4_t w1 = *(const float4_t*)(wout + o * 128 + dbase + 4);
#pragma unroll
        for (int j = 0; j < 4; ++j) {
          sum += bf2f((unsigned short)hv[j])     * w0[j];
          sum += bf2f((unsigned short)hv[j + 4]) * w1[j];
        }
      }
    out[(size_t)(n0 + s) * 10 + o] = sum;
  }
}

extern "C" void kernel_launch(void* const* d_in, const int* in_sizes, int n_in,
                              void* d_out, int out_size, void* d_ws, size_t ws_size,
                              hipStream_t stream) {
  const float* x    = (const float*)d_in[0];
  const float* wih0 = (const float*)d_in[1];
  const float* whh0 = (const float*)d_in[2];
  const float* bih0 = (const float*)d_in[3];
  const float* bhh0 = (const float*)d_in[4];
  const float* wih1 = (const float*)d_in[5];
  const float* whh1 = (const float*)d_in[6];
  const float* bih1 = (const float*)d_in[7];
  const float* bhh1 = (const float*)d_in[8];
  const float* wout = (const float*)d_in[9];
  const float* bout = (const float*)d_in[10];

  unsigned short* wp = (unsigned short*)d_ws;

  pack_weights<<<832, 256, 0, stream>>>(wih0, whh0, wih1, whh1, bih0, bhh0, wp);
  lstm_fused<<<256, 512, 0, stream>>>(x, wp, bih1, bhh1, wout, bout, (float*)d_out);
}